// Round 1
// baseline (75.175 us; speedup 1.0000x reference)
//
#include <hip/hip_runtime.h>
#include <math.h>

// RegimeFeatureExtractor: prices [B, T] f32 -> features [B, T, 6] f32
// Each output t depends only on prices[t-21 .. t]  (max window 20 + return halo).
// Direct windowed computation per thread; LDS-staged prices/log-prices/returns.

constexpr int BLOCK = 256;
constexpr int HALO  = 21;            // need r at g=t-20 => lp at g=t-21
constexpr int NS    = BLOCK + HALO;  // 277 staged elements per block
constexpr float EPS = 1e-8f;
constexpr float PI_HALF = 1.5707963267948966f;

__global__ __launch_bounds__(BLOCK)
void regime_kernel(const float* __restrict__ prices, float* __restrict__ out, int T) {
    __shared__ float sp[NS];   // prices (0 for g<0)
    __shared__ float slp[NS];  // log(p + eps)
    __shared__ float sr[NS];   // returns (0 for g<1)

    const int tid = threadIdx.x;
    const int t0  = blockIdx.x * BLOCK;
    const int row = blockIdx.y;
    const float* __restrict__ pr = prices + (size_t)row * T;

    // --- stage prices and log-prices ---
    for (int i = tid; i < NS; i += BLOCK) {
        int g = t0 - HALO + i;
        float p = (g >= 0) ? pr[g] : 0.0f;
        sp[i]  = p;
        slp[i] = logf(p + EPS);
    }
    __syncthreads();
    // --- returns: r[g] = lp[g] - lp[g-1] for g>=1, else 0 ---
    for (int i = tid; i < NS; i += BLOCK) {
        int g = t0 - HALO + i;
        sr[i] = (g >= 1 && i >= 1) ? (slp[i] - slp[i - 1]) : 0.0f;
    }
    __syncthreads();

    const int t  = t0 + tid;   // global time index (always < T; T % BLOCK == 0)
    const int lt = tid + HALO; // local index of t

    // --- windowed sums over returns (newest -> oldest) + price sums ---
    // zero-padding of sr/sp for out-of-range g makes unconditional loops exact.
    float s = 0.f, q = 0.f, ps = 0.f;
    float s5 = 0.f, q5 = 0.f, ps5 = 0.f, s10 = 0.f, q10 = 0.f;
    #pragma unroll
    for (int i = 0; i < 20; ++i) {
        float r = sr[lt - i];
        float p = sp[lt - i];
        s += r;
        q  = fmaf(r, r, q);
        ps += p;
        if (i == 4) { s5 = s; q5 = q; ps5 = ps; }
        if (i == 9) { s10 = s; q10 = q; }
    }
    const float s20 = s, q20 = q, ps20 = ps;

    // --- bipower: A = sum_{j=t-20}^{t-2} |r_j| * |r_{j+1}| ---
    float A = 0.f;
    float aprev = fabsf(sr[lt - 20]);
    #pragma unroll
    for (int i = 0; i < 19; ++i) {
        float b = fabsf(sr[lt - 19 + i]);
        A = fmaf(aprev, b, A);
        aprev = b;
    }

    // --- counts (fast uniform path for t >= 19) ---
    float c5, c10, c20, d5, d10, d20;
    if (t >= 19) {
        c5 = 5.f; c10 = 10.f; c20 = 20.f; d5 = 4.f; d10 = 9.f; d20 = 19.f;
    } else {
        int tp1 = t + 1;
        c5  = (float)(tp1 < 5  ? tp1 : 5);
        c10 = (float)(tp1 < 10 ? tp1 : 10);
        c20 = (float)(tp1 < 20 ? tp1 : 20);
        d5  = fmaxf(c5  - 1.f, 1.f);
        d10 = fmaxf(c10 - 1.f, 1.f);
        d20 = fmaxf(c20 - 1.f, 1.f);
    }

    // --- rolling std features ---
    float var5  = (q5  - s5  * s5  / c5 ) / d5;
    float var10 = (q10 - s10 * s10 / c10) / d10;
    float var20 = (q20 - s20 * s20 / c20) / d20;
    float std5  = sqrtf(fmaxf(var5,  0.f));
    float std10 = sqrtf(fmaxf(var10, 0.f));
    float std20 = sqrtf(fmaxf(var20, 0.f));
    const bool has2 = (t >= 1);  // cnt >= 2
    float f1 = has2 ? std5  : 1e-6f;
    float f2 = has2 ? std10 : 1e-6f;
    float f3 = has2 ? std20 : 1e-6f;

    // --- SMA crossover ---
    float m5  = ps5  / c5;
    float m20 = ps20 / c20;
    float f4 = (m5 - m20) / (m20 + EPS);

    // --- 5-step momentum ---
    // t<5 only occurs in the first chunk (t0==0), where sp[HALO] == p[0].
    float shifted = (t >= 5) ? sp[lt - 5] : sp[HALO];
    float f5 = (sp[lt] - shifted) / (shifted + EPS);

    // --- jump ratio rv / (bv + eps) ---
    float rv = f3 * f3;
    float bv = (t >= 20) ? A * PI_HALF : 0.f;
    float f6 = rv / (bv + EPS);

    // --- write [B, T, 6]; base*4 bytes is 8B-aligned ---
    size_t base = ((size_t)row * T + t) * 6;
    float2* o2 = (float2*)(out + base);
    o2[0] = make_float2(f1, f2);
    o2[1] = make_float2(f3, f4);
    o2[2] = make_float2(f5, f6);
}

extern "C" void kernel_launch(void* const* d_in, const int* in_sizes, int n_in,
                              void* d_out, int out_size, void* d_ws, size_t ws_size,
                              hipStream_t stream) {
    const float* prices = (const float*)d_in[0];
    float* out = (float*)d_out;
    const int T = 8192;                 // per reference setup_inputs()
    const int B = in_sizes[0] / T;
    dim3 grid(T / BLOCK, B);
    hipLaunchKernelGGL(regime_kernel, grid, dim3(BLOCK), 0, stream, prices, out, T);
}